// Round 12
// baseline (373.637 us; speedup 1.0000x reference)
//
#include <hip/hip_runtime.h>
#include <math.h>

#define B_   4096
#define S_   64
#define H_   128
#define N_   (B_*S_)

// ---- workspace float offsets ----
#define WS_WC    0        // [384][16]  combined obs->gi weights (padded f=16)
#define WS_BC    6144     // [384]      combined gi bias
#define WS_WAP   6528     // [128][16]  padded enc_air_w
#define WS_WQP   8576     // [128][128] wq * qln_w (fp32 copy)
#define WS_SQ    24960    // [128] row sums of wqp
#define WS_EQ    25088    // [128] wq@qln_b + bq
#define WS_KC    25216    // [128][4]  (wk*klnw)@enc_m_w
#define WS_EK1   25728    // [128] (wk*klnw)@enc_m_b
#define WS_SK    25856    // [128] rowsum(wk*klnw)
#define WS_EK2   25984    // [128] wk@kln_b + bk
#define WS_VC    26112    // [128][4]  wv@enc_m_w
#define WS_VB    26624    // [128] wv@enc_m_b + bv
#define WS_MV    26752    // [4] mean weights for keys_raw mean
#define WS_QQ    26756    // [16] 4x4 quadratic form for E[y^2]
#define WS_QLIN  26772    // [4]
#define WS_MBC   26776
#define WS_C0    26777
#define WS_PB    27392    // attnmlp packed bf16 B-frags: 65536 ushort (32768 floats)
#define WS_GB    60160    // gru packed bf16 B-frags: 65536 ushort (32768 floats)
#define WS_MU    92928    // [N_] float2 (mu, rs) LN stats
#define WS_AIRB  617216   // [N_][128] bf16 air_feat buffer (ushort)

typedef __attribute__((ext_vector_type(8))) short bf16x8;
typedef __attribute__((ext_vector_type(4))) float f32x4;

__device__ __forceinline__ float dot4(float4 a, float4 b){
    return fmaf(a.x,b.x, fmaf(a.y,b.y, fmaf(a.z,b.z, a.w*b.w)));
}
__device__ __forceinline__ unsigned short f2bf(float f){   // RNE fp32->bf16
    union { float f; unsigned u; } v; v.f = f;
    unsigned r = v.u + 0x7FFF + ((v.u >> 16) & 1);
    return (unsigned short)(r >> 16);
}
__device__ __forceinline__ float bf2f(unsigned short u){
    union { unsigned u; float f; } v; v.u = ((unsigned)u) << 16;
    return v.f;
}

// ---------------- precompute folded weights + attnmlp bf16 B-frags ----------------
__global__ void precompute_kernel(
    const float* __restrict__ enc_air_w, const float* __restrict__ enc_air_b,
    const float* __restrict__ enc_m_w,  const float* __restrict__ enc_m_b,
    const float* __restrict__ gru_wih,  const float* __restrict__ gru_bih,
    const float* __restrict__ qln_w, const float* __restrict__ qln_b,
    const float* __restrict__ kln_w, const float* __restrict__ kln_b,
    const float* __restrict__ attn_in_w, const float* __restrict__ attn_in_b,
    const float* __restrict__ attn_out_w,
    const float* __restrict__ mlp0_w, const float* __restrict__ mlp1_w,
    float* __restrict__ ws)
{
    int i = blockIdx.x*blockDim.x + threadIdx.x;
    if (i < 6144) {                       // Wc[o][f] = sum_k wih[o][k]*Wa[k][f]
        int o = i>>4, f = i&15; float a = 0.f;
        if (f < 15) for (int k=0;k<128;k++) a = fmaf(gru_wih[o*128+k], enc_air_w[k*15+f], a);
        ws[WS_WC+i] = a;
    } else if (i < 6528) {                // bc
        int o = i-6144; float a = gru_bih[o];
        for (int k=0;k<128;k++) a = fmaf(gru_wih[o*128+k], enc_air_b[k], a);
        ws[WS_BC+o] = a;
    } else if (i < 8576) {                // Wap padded
        int idx = i-6528; int j = idx>>4, f = idx&15;
        ws[WS_WAP+idx] = (f<15) ? enc_air_w[j*15+f] : 0.f;
    } else if (i < 24960) {               // wqp (fp32 copy)
        int idx = i-8576; int o = idx>>7, j = idx&127;
        ws[WS_WQP+idx] = attn_in_w[o*128+j]*qln_w[j];
    } else if (i < 25088) {               // sq
        int o = i-24960; float a=0.f;
        for (int j=0;j<128;j++) a = fmaf(attn_in_w[o*128+j], qln_w[j], a);
        ws[WS_SQ+o]=a;
    } else if (i < 25216) {               // eq
        int o = i-25088; float a = attn_in_b[o];
        for (int j=0;j<128;j++) a = fmaf(attn_in_w[o*128+j], qln_b[j], a);
        ws[WS_EQ+o]=a;
    } else if (i < 25728) {               // Kc
        int idx = i-25216; int o = idx>>2, f = idx&3; float a=0.f;
        for (int j=0;j<128;j++) a = fmaf(attn_in_w[(128+o)*128+j]*kln_w[j], enc_m_w[j*4+f], a);
        ws[WS_KC+idx]=a;
    } else if (i < 25856) {               // ek1
        int o = i-25728; float a=0.f;
        for (int j=0;j<128;j++) a = fmaf(attn_in_w[(128+o)*128+j]*kln_w[j], enc_m_b[j], a);
        ws[WS_EK1+o]=a;
    } else if (i < 25984) {               // sk
        int o = i-25856; float a=0.f;
        for (int j=0;j<128;j++) a = fmaf(attn_in_w[(128+o)*128+j], kln_w[j], a);
        ws[WS_SK+o]=a;
    } else if (i < 26112) {               // ek2
        int o = i-25984; float a = attn_in_b[128+o];
        for (int j=0;j<128;j++) a = fmaf(attn_in_w[(128+o)*128+j], kln_b[j], a);
        ws[WS_EK2+o]=a;
    } else if (i < 26624) {               // Vc
        int idx = i-26112; int o = idx>>2, f = idx&3; float a=0.f;
        for (int j=0;j<128;j++) a = fmaf(attn_in_w[(256+o)*128+j], enc_m_w[j*4+f], a);
        ws[WS_VC+idx]=a;
    } else if (i < 26752) {               // vb
        int o = i-26624; float a = attn_in_b[256+o];
        for (int j=0;j<128;j++) a = fmaf(attn_in_w[(256+o)*128+j], enc_m_b[j], a);
        ws[WS_VB+o]=a;
    } else if (i < 26756) {               // Mv
        int f = i-26752; float a=0.f;
        for (int j=0;j<128;j++) a += enc_m_w[j*4+f];
        ws[WS_MV+f]=a*(1.f/128.f);
    } else if (i < 26772) {               // QQ
        int idx = i-26756; int a4 = idx>>2, b4 = idx&3; float a=0.f;
        for (int j=0;j<128;j++) a = fmaf(enc_m_w[j*4+a4], enc_m_w[j*4+b4], a);
        ws[WS_QQ+idx]=a*(1.f/128.f);
    } else if (i < 26776) {               // qlin
        int f = i-26772; float a=0.f;
        for (int j=0;j<128;j++) a = fmaf(enc_m_b[j], enc_m_w[j*4+f], a);
        ws[WS_QLIN+f]=a*(2.f/128.f);
    } else if (i == 26776) {
        float a=0.f; for (int j=0;j<128;j++) a += enc_m_b[j];
        ws[WS_MBC]=a*(1.f/128.f);
    } else if (i == 26777) {
        float a=0.f; for (int j=0;j<128;j++) a = fmaf(enc_m_b[j], enc_m_b[j], a);
        ws[WS_C0]=a*(1.f/128.f);
    } else if (i >= 32768 && i < 98304) {
        // attnmlp packed bf16 B-fragments (R10 verified)
        int idx = i - 32768;              // 0..65535
        int i8 = idx & 7, l = (idx>>3)&63, p = (idx>>9)&3, wv = (idx>>11)&7, mm = idx>>14;
        int n = 16*wv + (l&15);
        int k = 32*p + ((l>>4)<<3) + i8;
        float v;
        if      (mm==0) v = attn_in_w[n*128+k]*qln_w[k];   // wqp (folded q-LN)
        else if (mm==1) v = attn_out_w[n*128+k];
        else if (mm==2) v = mlp0_w[n*128+k];
        else            v = mlp1_w[n*128+k];
        ((unsigned short*)(ws+WS_PB))[idx] = f2bf(v);
    }
}

// ---------------- pack GRU bf16 B-frags (R11 verified) ----------------
__global__ void pack_gru_kernel(const float* __restrict__ whh, float* __restrict__ ws)
{
    int idx = blockIdx.x*blockDim.x + threadIdx.x;   // [0, 65536)
    int i8 = idx&7, l=(idx>>3)&63, w=(idx>>9)&7, f=idx>>12;
    int n = 16*w + (l&15);
    int k = ((l>>4)<<3) + i8;       // 0..31 within chunk
    float v = 0.f;
    if (f < 5) {
        int kk = f*32 + k;
        if (kk < 128) v = whh[n*128 + kk];
        else { int kl = kk-128; if (kl<16) v = ws[WS_WC + n*16 + kl]; }
    } else if (f < 10) {
        int kk = (f-5)*32 + k;
        if (kk < 128) v = whh[(128+n)*128 + kk];
        else { int kl = kk-128; if (kl<16) v = ws[WS_WC + (128+n)*16 + kl]; }
    } else if (f < 14) {
        int kk = (f-10)*32 + k;
        v = whh[(256+n)*128 + kk];
    } else if (f == 14) {
        if (k < 16) v = ws[WS_WC + (256+n)*16 + k];
    } else {
        if (k < 16) v = ws[WS_WAP + n*16 + k];
    }
    ((unsigned short*)(ws+WS_GB))[idx] = f2bf(v);
}

// ---------------- Kernel A: GRU via bf16 MFMA, 1 barrier/step ----------------
// air_s double-buffered so the post-barrier phase (bf16 air store + LN stats)
// overlaps the next step's MFMA phase; obs commit moved pre-barrier.
__global__ __launch_bounds__(512) __attribute__((amdgpu_waves_per_eu(2, 2)))
void gru_kernel(
    const float* __restrict__ obs, const float* __restrict__ h0,
    const float* __restrict__ bhh, const float* __restrict__ ba,
    const float* __restrict__ ws,
    float* __restrict__ wsm, float* __restrict__ out)
{
    __shared__ __align__(16) unsigned short Abf[2][16*168];  // [token][k], pitch 168 shorts
    __shared__ float h32[2][16*132];
    __shared__ float air_s[2][16*132];

    const int t = threadIdx.x;
    const int w = t>>6;          // wave 0..7
    const int l = t&63;
    const int quad = l>>4;
    const int col  = l&15;
    const int jj   = 16*w + col; // output column j
    const int row0 = blockIdx.x*16;

    unsigned short* airb = (unsigned short*)(wsm + WS_AIRB);
    float2* mursp = (float2*)(wsm + WS_MU);

    // --- B-frags (loop-invariant; AGPR-parked) ---
    const unsigned short* gb = (const unsigned short*)(ws + WS_GB);
    bf16x8 bf[16];
    #pragma unroll
    for (int f=0; f<16; f++) bf[f] = *(const bf16x8*)&gb[(f*8 + w)*512 + l*8];

    const float bcrt = ws[WS_BC+jj]     + bhh[jj];
    const float bczt = ws[WS_BC+128+jj] + bhh[128+jj];
    const float bcn  = ws[WS_BC+256+jj];
    const float bhn  = bhh[256+jj];
    const float baj  = ba[jj];

    // --- init: h0 (fp32 + bf16), obs(0), zero pad k in [144,160) both buffers ---
    {
        int rr = t>>5, c0 = (t&31)*4;
        float4 hv = *(const float4*)&h0[(size_t)(row0+rr)*128 + c0];
        *(float4*)&h32[0][rr*132 + c0] = hv;
        unsigned long long pk = (unsigned long long)f2bf(hv.x)
              | ((unsigned long long)f2bf(hv.y)<<16)
              | ((unsigned long long)f2bf(hv.z)<<32)
              | ((unsigned long long)f2bf(hv.w)<<48);
        *(unsigned long long*)&Abf[0][rr*168 + c0] = pk;
    }
    if (t < 256){
        int tok = t>>4, c = t&15;
        float o = (c<15) ? obs[((size_t)(row0+tok)*64 + 0)*15 + c] : 0.f;
        Abf[0][tok*168 + 128 + c] = f2bf(o);
    } else {
        int idx = t-256; int tok = idx>>4, kk = 144 + (idx&15);
        Abf[0][tok*168 + kk] = 0;
        Abf[1][tok*168 + kk] = 0;
    }
    __syncthreads();

    for (int s=0; s<64; s++){
        const int b = s&1;
        const unsigned short* Ac = Abf[b];
        unsigned short*       An = Abf[1-b];
        const float* hc = h32[b];
        float*       hx = h32[1-b];

        // prefetch obs(s+1)
        float obs_pf = 0.f;
        if (t < 256){
            int tok = t>>4, c = t&15;
            int sn = (s<63) ? s+1 : s;
            obs_pf = (c<15) ? obs[((size_t)(row0+tok)*64 + sn)*15 + c] : 0.f;
        }

        // A-frags: token = col (m dim), k = 32p + quad*8 + i
        bf16x8 a0 = *(const bf16x8*)&Ac[col*168 +   0 + quad*8];
        bf16x8 a1 = *(const bf16x8*)&Ac[col*168 +  32 + quad*8];
        bf16x8 a2 = *(const bf16x8*)&Ac[col*168 +  64 + quad*8];
        bf16x8 a3 = *(const bf16x8*)&Ac[col*168 +  96 + quad*8];
        bf16x8 a4 = *(const bf16x8*)&Ac[col*168 + 128 + quad*8];

        f32x4 aR = {0.f,0.f,0.f,0.f};
        f32x4 aZ = {0.f,0.f,0.f,0.f};
        f32x4 aN = {0.f,0.f,0.f,0.f};
        f32x4 aG = {0.f,0.f,0.f,0.f};
        f32x4 aE = {0.f,0.f,0.f,0.f};
        aR = __builtin_amdgcn_mfma_f32_16x16x32_bf16(a0, bf[0],  aR, 0,0,0);
        aR = __builtin_amdgcn_mfma_f32_16x16x32_bf16(a1, bf[1],  aR, 0,0,0);
        aR = __builtin_amdgcn_mfma_f32_16x16x32_bf16(a2, bf[2],  aR, 0,0,0);
        aR = __builtin_amdgcn_mfma_f32_16x16x32_bf16(a3, bf[3],  aR, 0,0,0);
        aR = __builtin_amdgcn_mfma_f32_16x16x32_bf16(a4, bf[4],  aR, 0,0,0);
        aZ = __builtin_amdgcn_mfma_f32_16x16x32_bf16(a0, bf[5],  aZ, 0,0,0);
        aZ = __builtin_amdgcn_mfma_f32_16x16x32_bf16(a1, bf[6],  aZ, 0,0,0);
        aZ = __builtin_amdgcn_mfma_f32_16x16x32_bf16(a2, bf[7],  aZ, 0,0,0);
        aZ = __builtin_amdgcn_mfma_f32_16x16x32_bf16(a3, bf[8],  aZ, 0,0,0);
        aZ = __builtin_amdgcn_mfma_f32_16x16x32_bf16(a4, bf[9],  aZ, 0,0,0);
        aN = __builtin_amdgcn_mfma_f32_16x16x32_bf16(a0, bf[10], aN, 0,0,0);
        aN = __builtin_amdgcn_mfma_f32_16x16x32_bf16(a1, bf[11], aN, 0,0,0);
        aN = __builtin_amdgcn_mfma_f32_16x16x32_bf16(a2, bf[12], aN, 0,0,0);
        aN = __builtin_amdgcn_mfma_f32_16x16x32_bf16(a3, bf[13], aN, 0,0,0);
        aG = __builtin_amdgcn_mfma_f32_16x16x32_bf16(a4, bf[14], aG, 0,0,0);
        aE = __builtin_amdgcn_mfma_f32_16x16x32_bf16(a4, bf[15], aE, 0,0,0);

        // finalize: D row = token = quad*4+reg, col = jj (per-lane)
        #pragma unroll
        for (int reg=0; reg<4; reg++){
            int tok = quad*4 + reg;
            float rg = 1.f/(1.f+__expf(-(aR[reg] + bcrt)));
            float zg = 1.f/(1.f+__expf(-(aZ[reg] + bczt)));
            float nx = fmaf(rg, aN[reg] + bhn, aG[reg] + bcn);
            float e2 = __expf(2.f*nx);
            float ng = 1.f - 2.f/(e2+1.f);            // tanh(nx)
            float hold = hc[tok*132 + jj];
            float hn = fmaf(zg, hold-ng, ng);         // (1-z)n + z*h
            hx[tok*132 + jj] = hn;
            An[tok*168 + jj] = f2bf(hn);
            air_s[b][tok*132 + jj] = hn + (aE[reg] + baj);
            if (s==63) out[(size_t)N_ + (size_t)(row0+tok)*128 + jj] = hn;
        }
        // commit obs(s+1) into An chunk 4 (pre-barrier; only needed next step)
        if (t < 256){
            int tok = t>>4, c = t&15;
            An[tok*168 + 128 + c] = f2bf(obs_pf);
        }
        __syncthreads();   // single barrier: Ac/hc reads done; An/hx/air_s[b] complete

        // post: bf16 air store + LN stats (overlaps next step's MFMA phase)
        {
            int rr = t>>5, c0 = (t&31)*4;
            float4 av = *(const float4*)&air_s[b][rr*132 + c0];
            unsigned long long pk = (unsigned long long)f2bf(av.x)
                  | ((unsigned long long)f2bf(av.y)<<16)
                  | ((unsigned long long)f2bf(av.z)<<32)
                  | ((unsigned long long)f2bf(av.w)<<48);
            size_t n = (size_t)(row0+rr)*64 + s;
            *(unsigned long long*)&airb[n*128 + c0] = pk;
            float sm = av.x+av.y+av.z+av.w;
            float s2 = fmaf(av.x,av.x, fmaf(av.y,av.y, fmaf(av.z,av.z, av.w*av.w)));
            #pragma unroll
            for (int m=1;m<32;m<<=1){ sm += __shfl_xor(sm,m); s2 += __shfl_xor(s2,m); }
            if ((t&31)==0){
                float mu = sm*(1.f/128.f);
                float var = s2*(1.f/128.f) - mu*mu;
                float2 mr; mr.x = mu; mr.y = rsqrtf(var+1e-5f);
                mursp[n] = mr;
            }
        }
        // no second barrier: next step's writes touch the other buffers only
    }
}

// ---------------- Kernel B: attention + MLP via bf16 MFMA ----------------
// Staging now reads bf16 air directly + precomputed LN stats.
__global__ __launch_bounds__(512) void attnmlp_kernel(
    const float* __restrict__ obs, const float* __restrict__ bo,
    const float* __restrict__ ws,
    const float* __restrict__ b0, const float* __restrict__ b1,
    const float* __restrict__ fcw, const float* __restrict__ fcb,
    const float* __restrict__ wsm, float* __restrict__ out)
{
    __shared__ __align__(16) unsigned short X_bf[16*136];
    __shared__ __align__(16) unsigned short Y_bf[16*136];
    __shared__ __align__(16) unsigned short Z_bf[16*136];
    __shared__ float obs_m[16][12];
    __shared__ float part[16][2][8];
    __shared__ float attn_s[16][4][2];
    __shared__ float mu_s[16], rs_s[16];
    __shared__ float kmu_s[16][2], krs_s[16][2];
    __shared__ int   kmask_s[16][2];
    __shared__ int   bothm_s[16];

    const int t = threadIdx.x;
    const int w = t>>6;
    const int l = t&63;
    const int quad = l>>4;
    const int col  = l&15;
    const int jj   = 16*w + col;
    const int n0 = blockIdx.x*16;

    const unsigned short* pbu = (const unsigned short*)(ws + WS_PB);
    const unsigned short* airb = (const unsigned short*)(wsm + WS_AIRB);
    const float2* mursp = (const float2*)(wsm + WS_MU);

    // ---- stage X (bf16 direct) + LN stats load + missile staging/stats ----
    {
        int rr = t>>5, c0 = (t&31)*4;
        unsigned long long v = *(const unsigned long long*)&airb[(size_t)(n0+rr)*128 + c0];
        *(unsigned long long*)&X_bf[rr*136 + c0] = v;
    }
    if (t < 16){
        float2 mr = mursp[n0 + t];
        mu_s[t] = mr.x; rs_s[t] = mr.y;
    }
    if (t>=128 && t<256){
        int idx = t-128; int rr = idx>>3, f = idx&7;
        obs_m[rr][f] = obs[(size_t)(n0+rr)*15 + f];
    }
    if (t>=32 && t<64){
        int idx = t-32; int rr = idx&15, mi = idx>>4;
        const float* mp = &obs[(size_t)(n0+rr)*15 + mi*4];
        float m0=mp[0], m1=mp[1], m2=mp[2], m3=mp[3];
        const float tol1 = 1e-8f + 1e-5f, tol0 = 1e-8f;
        kmask_s[rr][mi] = (fabsf(m0-1.f)<=tol1)&&(fabsf(m1)<=tol0)&&
                          (fabsf(m2-1.f)<=tol1)&&(fabsf(m3)<=tol0);
        float mv[4]={m0,m1,m2,m3};
        float mu = ws[WS_MBC];
        #pragma unroll
        for (int f=0;f<4;f++) mu = fmaf(ws[WS_MV+f], mv[f], mu);
        float e2 = ws[WS_C0];
        #pragma unroll
        for (int a4=0;a4<4;a4++){
            e2 = fmaf(ws[WS_QLIN+a4], mv[a4], e2);
            #pragma unroll
            for (int b4=0;b4<4;b4++) e2 = fmaf(ws[WS_QQ+a4*4+b4]*mv[a4], mv[b4], e2);
        }
        float var = e2 - mu*mu;
        kmu_s[rr][mi]=mu; krs_s[rr][mi]=rsqrtf(var+1e-5f);
    }
    __syncthreads();

    // ---- q matvec (MFMA) + scores ----
    {
        f32x4 acc = {0.f,0.f,0.f,0.f};
        #pragma unroll
        for (int p=0;p<4;p++){
            bf16x8 a = *(const bf16x8*)&X_bf[col*136 + p*32 + quad*8];
            bf16x8 b = *(const bf16x8*)&pbu[((0*32 + w*4 + p)*64 + l)*8];
            acc = __builtin_amdgcn_mfma_f32_16x16x32_bf16(a, b, acc, 0, 0, 0);
        }
        const float sqj = ws[WS_SQ+jj], eqj = ws[WS_EQ+jj];
        const float4 kcj = ((const float4*)(ws+WS_KC))[jj];
        const float ek1j = ws[WS_EK1+jj], skj = ws[WS_SK+jj], ek2j = ws[WS_EK2+jj];
        float p0v[4], p1v[4];
        #pragma unroll
        for (int reg=0;reg<4;reg++){
            int tok = quad*4 + reg;
            float qv = fmaf(rs_s[tok], acc[reg] - mu_s[tok]*sqj, eqj);
            float4 m0v = *(const float4*)&obs_m[tok][0];
            float4 m1v = *(const float4*)&obs_m[tok][4];
            float k0 = fmaf(krs_s[tok][0], dot4(kcj,m0v)+ek1j - kmu_s[tok][0]*skj, ek2j);
            float k1 = fmaf(krs_s[tok][1], dot4(kcj,m1v)+ek1j - kmu_s[tok][1]*skj, ek2j);
            p0v[reg] = qv*k0; p1v[reg] = qv*k1;
        }
        #pragma unroll
        for (int m=1;m<16;m<<=1){
            #pragma unroll
            for (int reg=0;reg<4;reg++){
                p0v[reg] += __shfl_xor(p0v[reg], m);
                p1v[reg] += __shfl_xor(p1v[reg], m);
            }
        }
        if (col==0){
            #pragma unroll
            for (int reg=0;reg<4;reg++){
                part[quad*4+reg][0][w] = p0v[reg];
                part[quad*4+reg][1][w] = p1v[reg];
            }
        }
    }
    __syncthreads();

    if (t<64){
        int rr = t&15, hd = t>>4;
        float s0 = part[rr][0][2*hd] + part[rr][0][2*hd+1];
        float s1 = part[rr][1][2*hd] + part[rr][1][2*hd+1];
        const float scale = 0.17677669529663687f;  // 1/sqrt(32)
        s0 *= scale; s1 *= scale;
        int m0 = kmask_s[rr][0], m1 = kmask_s[rr][1];
        float a0, a1;
        if (m0 && m1) { a0=0.f; a1=0.f; if (hd==0) bothm_s[rr]=1; }
        else {
            if (hd==0) bothm_s[rr]=0;
            if (m0)      { a0=0.f; a1=1.f; }
            else if (m1) { a0=1.f; a1=0.f; }
            else {
                float mx = fmaxf(s0,s1);
                float e0 = __expf(s0-mx), e1 = __expf(s1-mx);
                float inv = 1.f/(e0+e1);
                a0 = e0*inv; a1 = e1*inv;
            }
        }
        attn_s[rr][hd][0]=a0; attn_s[rr][hd][1]=a1;
    }
    __syncthreads();

    {
        const int hd = w>>1;
        const float4 vcj = ((const float4*)(ws+WS_VC))[jj];
        const float vbj = ws[WS_VB+jj];
        #pragma unroll
        for (int reg=0;reg<4;reg++){
            int tok = quad*4 + reg;
            float4 m0v = *(const float4*)&obs_m[tok][0];
            float4 m1v = *(const float4*)&obs_m[tok][4];
            float v0 = dot4(vcj,m0v)+vbj, v1 = dot4(vcj,m1v)+vbj;
            float cx = attn_s[tok][hd][0]*v0 + attn_s[tok][hd][1]*v1;
            Y_bf[tok*136 + jj] = f2bf(cx);
        }
    }
    __syncthreads();

    {
        f32x4 acc = {0.f,0.f,0.f,0.f};
        #pragma unroll
        for (int p=0;p<4;p++){
            bf16x8 a = *(const bf16x8*)&Y_bf[col*136 + p*32 + quad*8];
            bf16x8 b = *(const bf16x8*)&pbu[((1*32 + w*4 + p)*64 + l)*8];
            acc = __builtin_amdgcn_mfma_f32_16x16x32_bf16(a, b, acc, 0, 0, 0);
        }
        const float boj = bo[jj];
        #pragma unroll
        for (int reg=0;reg<4;reg++){
            int tok = quad*4 + reg;
            float xv = bf2f(X_bf[tok*136 + jj]);
            float ao = bothm_s[tok] ? 0.f : (acc[reg] + boj);
            Z_bf[tok*136 + jj] = f2bf(xv + ao);
        }
    }
    __syncthreads();

    {
        f32x4 acc = {0.f,0.f,0.f,0.f};
        #pragma unroll
        for (int p=0;p<4;p++){
            bf16x8 a = *(const bf16x8*)&Z_bf[col*136 + p*32 + quad*8];
            bf16x8 b = *(const bf16x8*)&pbu[((2*32 + w*4 + p)*64 + l)*8];
            acc = __builtin_amdgcn_mfma_f32_16x16x32_bf16(a, b, acc, 0, 0, 0);
        }
        const float b0j = b0[jj];
        #pragma unroll
        for (int reg=0;reg<4;reg++){
            int tok = quad*4 + reg;
            float v = acc[reg] + b0j;
            v = fmaxf(v, 0.01f*v);
            Y_bf[tok*136 + jj] = f2bf(v);
        }
    }
    __syncthreads();

    {
        f32x4 acc = {0.f,0.f,0.f,0.f};
        #pragma unroll
        for (int p=0;p<4;p++){
            bf16x8 a = *(const bf16x8*)&Y_bf[col*136 + p*32 + quad*8];
            bf16x8 b = *(const bf16x8*)&pbu[((3*32 + w*4 + p)*64 + l)*8];
            acc = __builtin_amdgcn_mfma_f32_16x16x32_bf16(a, b, acc, 0, 0, 0);
        }
        const float b1j = b1[jj], fcj = fcw[jj];
        float pv[4];
        #pragma unroll
        for (int reg=0;reg<4;reg++){
            float v = acc[reg] + b1j;
            v = fmaxf(v, 0.01f*v);
            pv[reg] = v * fcj;
        }
        #pragma unroll
        for (int m=1;m<16;m<<=1){
            #pragma unroll
            for (int reg=0;reg<4;reg++) pv[reg] += __shfl_xor(pv[reg], m);
        }
        if (col==0){
            #pragma unroll
            for (int reg=0;reg<4;reg++) part[quad*4+reg][0][w] = pv[reg];
        }
    }
    __syncthreads();
    if (t<16){
        float a = 0.f;
        #pragma unroll
        for (int k=0;k<8;k++) a += part[t][0][k];
        out[n0 + t] = a + fcb[0];
    }
}

extern "C" void kernel_launch(void* const* d_in, const int* in_sizes, int n_in,
                              void* d_out, int out_size, void* d_ws, size_t ws_size,
                              hipStream_t stream) {
    const float* obs       = (const float*)d_in[0];
    const float* h0        = (const float*)d_in[1];
    const float* enc_air_w = (const float*)d_in[2];
    const float* enc_air_b = (const float*)d_in[3];
    const float* enc_m_w   = (const float*)d_in[4];
    const float* enc_m_b   = (const float*)d_in[5];
    const float* gru_wih   = (const float*)d_in[6];
    const float* gru_whh   = (const float*)d_in[7];
    const float* gru_bih   = (const float*)d_in[8];
    const float* gru_bhh   = (const float*)d_in[9];
    const float* qln_w     = (const float*)d_in[10];
    const float* qln_b     = (const float*)d_in[11];
    const float* kln_w     = (const float*)d_in[12];
    const float* kln_b     = (const float*)d_in[13];
    const float* attn_in_w = (const float*)d_in[14];
    const float* attn_in_b = (const float*)d_in[15];
    const float* attn_out_w= (const float*)d_in[16];
    const float* attn_out_b= (const float*)d_in[17];
    const float* mlp0_w    = (const float*)d_in[18];
    const float* mlp0_b    = (const float*)d_in[19];
    const float* mlp1_w    = (const float*)d_in[20];
    const float* mlp1_b    = (const float*)d_in[21];
    const float* fco_w     = (const float*)d_in[22];
    const float* fco_b     = (const float*)d_in[23];
    float* out = (float*)d_out;
    float* ws  = (float*)d_ws;

    precompute_kernel<<<dim3(384), dim3(256), 0, stream>>>(
        enc_air_w, enc_air_b, enc_m_w, enc_m_b, gru_wih, gru_bih,
        qln_w, qln_b, kln_w, kln_b, attn_in_w, attn_in_b,
        attn_out_w, mlp0_w, mlp1_w, ws);

    pack_gru_kernel<<<dim3(256), dim3(256), 0, stream>>>(gru_whh, ws);

    gru_kernel<<<dim3(256), dim3(512), 0, stream>>>(
        obs, h0, gru_bhh, enc_air_b, ws, ws, out);

    attnmlp_kernel<<<dim3(N_/16), dim3(512), 0, stream>>>(
        obs, attn_out_b, ws,
        mlp0_b, mlp1_b, fco_w, fco_b,
        ws, out);
}